// Round 1
// baseline (152.483 us; speedup 1.0000x reference)
//
#include <hip/hip_runtime.h>
#include <math.h>

// Problem constants (from reference): VOCAB=32000, D=128, B=8, R=100, C=64, T=32
constexpr int D      = 128;
constexpr int T      = 32;
constexpr int NCELLS = 8 * 100 * 64;   // 51200
constexpr int WAVES_PER_BLOCK = 4;     // 256 threads

// One wave (64 lanes) per cell.
// Lane l owns embedding dims d = 2l, 2l+1 (float2 => each gathered row load is
// one fully-coalesced 512B wave transaction).
__global__ __launch_bounds__(256) void GeluAvgEmbed_kernel(
    const int*   __restrict__ x,       // [NCELLS, T]
    const float* __restrict__ W,       // [VOCAB, D]
    const float* __restrict__ w_pred,  // [1, D]
    const float* __restrict__ b_pred,  // [1]
    float*       __restrict__ out)     // [NCELLS]
{
    const int wave = threadIdx.x >> 6;
    const int lane = threadIdx.x & 63;
    const int cell = blockIdx.x * WAVES_PER_BLOCK + wave;
    if (cell >= NCELLS) return;

    // Load the 32 token indices for this cell once (coalesced 128B),
    // duplicated across the two half-waves; broadcast per-token via shfl.
    const int* xp = x + (long)cell * T;
    int myidx = xp[lane & (T - 1)];

    const float2* __restrict__ W2 = reinterpret_cast<const float2*>(W);

    float2 acc = make_float2(0.0f, 0.0f);
    #pragma unroll
    for (int t = 0; t < T; ++t) {
        int row = __shfl(myidx, t, 64);           // token id, wave-uniform
        float2 v = W2[(long)row * (D / 2) + lane]; // coalesced 512B/wave
        acc.x += v.x;
        acc.y += v.y;
    }

    // mean over T
    const float inv_t = 1.0f / (float)T;
    float p0 = acc.x * inv_t;
    float p1 = acc.y * inv_t;

    // exact (erf) GELU
    const float inv_sqrt2 = 0.70710678118654752440f;
    float a0 = 0.5f * p0 * (1.0f + erff(p0 * inv_sqrt2));
    float a1 = 0.5f * p1 * (1.0f + erff(p1 * inv_sqrt2));

    // dot with w_pred
    float2 wv = reinterpret_cast<const float2*>(w_pred)[lane];
    float s = a0 * wv.x + a1 * wv.y;

    // wave-wide reduction (64 lanes)
    #pragma unroll
    for (int off = 32; off >= 1; off >>= 1)
        s += __shfl_down(s, off, 64);

    if (lane == 0)
        out[cell] = s + b_pred[0];
}

extern "C" void kernel_launch(void* const* d_in, const int* in_sizes, int n_in,
                              void* d_out, int out_size, void* d_ws, size_t ws_size,
                              hipStream_t stream) {
    const int*   x      = (const int*)  d_in[0];
    const float* W      = (const float*)d_in[1];
    const float* w_pred = (const float*)d_in[2];
    const float* b_pred = (const float*)d_in[3];
    float*       out    = (float*)d_out;

    const int blocks = (NCELLS + WAVES_PER_BLOCK - 1) / WAVES_PER_BLOCK; // 12800
    GeluAvgEmbed_kernel<<<blocks, 256, 0, stream>>>(x, W, w_pred, b_pred, out);
}

// Round 2
// 106.361 us; speedup vs baseline: 1.4336x; 1.4336x over previous
//
#include <hip/hip_runtime.h>
#include <math.h>
#include <string.h>

constexpr int VOCAB  = 32000;
constexpr int D      = 128;
constexpr int T      = 32;
constexpr int NCELLS = 8 * 100 * 64;   // 51200
constexpr int WAVES_PER_BLOCK = 4;     // 256 threads

// ---- bf16 helpers (manual RTN-even; inputs are finite randn, no NaN concerns)
__device__ inline ushort f2bf(float f) {
    uint32_t u;
    memcpy(&u, &f, 4);
    u += 0x7FFFu + ((u >> 16) & 1u);   // round to nearest even
    return (ushort)(u >> 16);
}
__device__ inline float bf2f(ushort h) {
    uint32_t u = ((uint32_t)h) << 16;
    float f;
    memcpy(&f, &u, 4);
    return f;
}

// Kernel 1: convert W_embed f32 -> bf16 into workspace. 32000*128 = 4.096M elems.
__global__ __launch_bounds__(256) void convert_W_kernel(
    const float* __restrict__ W, ushort* __restrict__ Wb)
{
    const int i = blockIdx.x * blockDim.x + threadIdx.x;  // group of 4 elements
    // total groups = VOCAB*D/4 = 1,024,000 -> grid 4000 x 256 exact
    float4 v = reinterpret_cast<const float4*>(W)[i];
    ushort4 o;
    o.x = f2bf(v.x);
    o.y = f2bf(v.y);
    o.z = f2bf(v.z);
    o.w = f2bf(v.w);
    reinterpret_cast<ushort4*>(Wb)[i] = o;
}

// Kernel 2: one wave per cell. Each half-wave (32 lanes) loads one full 256B
// bf16 row per iteration (8B/lane), so a wave covers 2 tokens/iter (16 iters).
__global__ __launch_bounds__(256) void gather_kernel(
    const int*    __restrict__ x,       // [NCELLS, T]
    const ushort* __restrict__ Wb,      // [VOCAB, D] bf16 bits
    const float*  __restrict__ w_pred,  // [1, D]
    const float*  __restrict__ b_pred,  // [1]
    float*        __restrict__ out)     // [NCELLS]
{
    const int wave = threadIdx.x >> 6;
    const int lane = threadIdx.x & 63;
    const int cell = blockIdx.x * WAVES_PER_BLOCK + wave;
    if (cell >= NCELLS) return;

    const int c    = lane & 31;   // dim-chunk index: dims 4c..4c+3
    const int half = lane >> 5;   // which token of the pair this half-wave does

    // token ids: lane l holds x[cell, l&31] (coalesced 128B, duplicated halves)
    int myidx = x[(long)cell * T + c];

    float a0 = 0.f, a1 = 0.f, a2 = 0.f, a3 = 0.f;
    #pragma unroll
    for (int t = 0; t < T / 2; ++t) {
        int row = __shfl(myidx, 2 * t + half, 64);  // per-half-wave token id
        ushort4 v = reinterpret_cast<const ushort4*>(Wb + (size_t)row * D)[c];
        a0 += bf2f(v.x);
        a1 += bf2f(v.y);
        a2 += bf2f(v.z);
        a3 += bf2f(v.w);
    }
    // combine the two half-wave token partials
    a0 += __shfl_xor(a0, 32, 64);
    a1 += __shfl_xor(a1, 32, 64);
    a2 += __shfl_xor(a2, 32, 64);
    a3 += __shfl_xor(a3, 32, 64);

    // mean over T
    const float inv_t = 1.0f / (float)T;
    a0 *= inv_t; a1 *= inv_t; a2 *= inv_t; a3 *= inv_t;

    // exact (erf) GELU
    const float is2 = 0.70710678118654752440f;
    float g0 = 0.5f * a0 * (1.0f + erff(a0 * is2));
    float g1 = 0.5f * a1 * (1.0f + erff(a1 * is2));
    float g2 = 0.5f * a2 * (1.0f + erff(a2 * is2));
    float g3 = 0.5f * a3 * (1.0f + erff(a3 * is2));

    // dot with w_pred (f32)
    float4 wv = reinterpret_cast<const float4*>(w_pred)[c];
    float s = g0 * wv.x + g1 * wv.y + g2 * wv.z + g3 * wv.w;

    // reduce over the 32 dim-chunks (values duplicated across halves, so
    // xor-reduction within 16..1 suffices)
    #pragma unroll
    for (int off = 16; off >= 1; off >>= 1)
        s += __shfl_xor(s, off, 64);

    if (lane == 0)
        out[cell] = s + b_pred[0];
}

extern "C" void kernel_launch(void* const* d_in, const int* in_sizes, int n_in,
                              void* d_out, int out_size, void* d_ws, size_t ws_size,
                              hipStream_t stream) {
    const int*   x      = (const int*)  d_in[0];
    const float* W      = (const float*)d_in[1];
    const float* w_pred = (const float*)d_in[2];
    const float* b_pred = (const float*)d_in[3];
    float*       out    = (float*)d_out;
    ushort*      Wb     = (ushort*)d_ws;   // needs VOCAB*D*2 = 8.192 MB

    const int conv_groups = VOCAB * D / 4;                 // 1,024,000
    convert_W_kernel<<<conv_groups / 256, 256, 0, stream>>>(W, Wb);

    const int blocks = (NCELLS + WAVES_PER_BLOCK - 1) / WAVES_PER_BLOCK; // 12800
    gather_kernel<<<blocks, 256, 0, stream>>>(x, Wb, w_pred, b_pred, out);
}